// Round 7
// baseline (306.840 us; speedup 1.0000x reference)
//
#include <hip/hip_runtime.h>
#include <hip/hip_bf16.h>

#define B_ 2
#define T_ 2048
#define D_ 1024
#define H_ 16
#define HD_ 64
#define NP_ 3
#define P_ 256

// log2(e)/sqrt(64): folded into Q in the QKV-GEMM epilogue; softmax in exp2 domain
#define SCALE2 0.18033688011112042f

typedef short bf16x8 __attribute__((ext_vector_type(8)));
typedef float f32x4 __attribute__((ext_vector_type(4)));

__device__ __forceinline__ float bf2f(__hip_bfloat16 v) { return __bfloat162float(v); }
__device__ __forceinline__ __hip_bfloat16 f2bf(float v) { return __float2bfloat16(v); }

#define GLOAD_LDS16(gp, lp) \
    __builtin_amdgcn_global_load_lds( \
        (const __attribute__((address_space(1))) void*)(gp), \
        (__attribute__((address_space(3))) void*)(lp), 16, 0, 0)

// ---------------------------------------------------------------------------
// Kernel 0: input dtype detect (fp32 reinterpreted as bf16 shows huge exps).
// ---------------------------------------------------------------------------
__global__ __launch_bounds__(256) void detect_kernel(
    const unsigned short* __restrict__ xs, int* __restrict__ flag)
{
    __shared__ int cnt;
    if (threadIdx.x == 0) cnt = 0;
    __syncthreads();
    int bad = 0;
    for (int i = threadIdx.x; i < 16384; i += 256) {
        int e = (xs[i] >> 7) & 0xFF;
        if (e >= 0xB8) bad++;
    }
    if (bad) atomicAdd(&cnt, bad);
    __syncthreads();
    if (threadIdx.x == 0) *flag = (cnt >= 8) ? 1 : 0;
}

// fp32-or-bf16 -> bf16 (weights for MFMA)
__global__ __launch_bounds__(256) void cvt16_kernel(
    const void* __restrict__ src, __hip_bfloat16* __restrict__ dst,
    int n, const int* __restrict__ flag)
{
    int i = blockIdx.x * 256 + threadIdx.x;
    if (i >= n) return;
    dst[i] = (*flag) ? f2bf(((const float*)src)[i])
                     : ((const __hip_bfloat16*)src)[i];
}

// all 7 small fp32 parameter arrays in one launch -> contiguous fp32 block
__global__ __launch_bounds__(256) void cvt_small_kernel(
    const void* __restrict__ g,  const void* __restrict__ b,
    const void* __restrict__ n1, const void* __restrict__ n2,
    const void* __restrict__ ang, const void* __restrict__ gt,
    const void* __restrict__ bi,
    float* __restrict__ dst, const int* __restrict__ flag)
{
    int i = blockIdx.x * 256 + threadIdx.x;
    if (i >= 11008) return;
    const void* src; int off;
    if      (i < 1024) { src = g;   off = i; }
    else if (i < 2048) { src = b;   off = i - 1024; }
    else if (i < 3072) { src = n1;  off = i - 2048; }
    else if (i < 4096) { src = n2;  off = i - 3072; }
    else if (i < 4864) { src = ang; off = i - 4096; }
    else if (i < 7936) { src = gt;  off = i - 4864; }
    else               { src = bi;  off = i - 7936; }
    dst[i] = (*flag) ? ((const float*)src)[off]
                     : bf2f(((const __hip_bfloat16*)src)[off]);
}

// ---------------------------------------------------------------------------
// Kernel 1: h = rmsnorm(x,w)*gamma+beta (bf16 out) and xcopy = x as fp32.
// ---------------------------------------------------------------------------
__global__ __launch_bounds__(256) void rmsnorm1_kernel(
    const void* __restrict__ xraw,
    const float* __restrict__ gamma,
    const float* __restrict__ beta,
    const float* __restrict__ w,
    const int* __restrict__ flag,
    __hip_bfloat16* __restrict__ out,
    float* __restrict__ xcopy)
{
    int row = blockIdx.x;
    int t = threadIdx.x;
    int f = *flag;
    float eps = f ? 1.1920929e-7f : 0.0078125f;
    float v[4];
    if (f) {
        const float4 xv = ((const float4*)((const float*)xraw + (size_t)row * D_))[t];
        v[0] = xv.x; v[1] = xv.y; v[2] = xv.z; v[3] = xv.w;
    } else {
        const __hip_bfloat16* xr = (const __hip_bfloat16*)xraw + (size_t)row * D_;
#pragma unroll
        for (int c = 0; c < 4; c++) v[c] = bf2f(xr[t * 4 + c]);
    }
    float ss = 0.f;
#pragma unroll
    for (int c = 0; c < 4; c++) ss += v[c] * v[c];
#pragma unroll
    for (int m = 32; m; m >>= 1) ss += __shfl_xor(ss, m, 64);
    __shared__ float red[4];
    int wv = t >> 6;
    if ((t & 63) == 0) red[wv] = ss;
    __syncthreads();
    float scale = rsqrtf((red[0] + red[1] + red[2] + red[3]) * (1.0f / D_) + eps);
#pragma unroll
    for (int c = 0; c < 4; c++) {
        int e = t * 4 + c;
        size_t idx = (size_t)row * D_ + e;
        xcopy[idx] = v[c];
        out[idx] = f2bf(v[c] * scale * w[e] * gamma[e] + beta[e]);
    }
}

// ---------------------------------------------------------------------------
// Kernel 2: C = A @ B^T bf16 out. 128x128, BK=32, global_load_lds width=16.
// Columns n < nscale get scaled by qscale (folds attention score scale into Q).
// ---------------------------------------------------------------------------
__global__ __launch_bounds__(256) void gemm_bt_bf16_kernel(
    const __hip_bfloat16* __restrict__ A,
    const __hip_bfloat16* __restrict__ Bm,
    __hip_bfloat16* __restrict__ C,
    int M, int N, int K, int nscale, float qscale)
{
    __shared__ __attribute__((aligned(16))) __hip_bfloat16 As[128 * 32];
    __shared__ __attribute__((aligned(16))) __hip_bfloat16 Bs[128 * 32];
    int tid = threadIdx.x;
    int bm = blockIdx.y, bn = blockIdx.x;
    int lane = tid & 63, wv = tid >> 6;
    int wm = wv >> 1, wn = wv & 1;
    int q = lane >> 4, mr = lane & 15;

    f32x4 acc[4][4] = {};

    for (int k0 = 0; k0 < K; k0 += 32) {
#pragma unroll
        for (int s = 0; s < 2; s++) {
            int e = (s * 256 + tid) * 8;
            int r = e >> 5, c = e & 31;
            GLOAD_LDS16(&A[(size_t)(bm * 128 + r) * K + k0 + c], &As[e]);
            GLOAD_LDS16(&Bm[(size_t)(bn * 128 + r) * K + k0 + c], &Bs[e]);
        }
        __syncthreads();
        bf16x8 af[4], bfr[4];
#pragma unroll
        for (int i = 0; i < 4; i++)
            af[i] = *(const bf16x8*)(&As[(wm * 64 + i * 16 + mr) * 32 + q * 8]);
#pragma unroll
        for (int j = 0; j < 4; j++)
            bfr[j] = *(const bf16x8*)(&Bs[(wn * 64 + j * 16 + mr) * 32 + q * 8]);
#pragma unroll
        for (int i = 0; i < 4; i++)
#pragma unroll
            for (int j = 0; j < 4; j++)
                acc[i][j] = __builtin_amdgcn_mfma_f32_16x16x32_bf16(af[i], bfr[j], acc[i][j], 0, 0, 0);
        __syncthreads();
    }

#pragma unroll
    for (int i = 0; i < 4; i++)
#pragma unroll
        for (int r = 0; r < 4; r++) {
            int m = bm * 128 + wm * 64 + i * 16 + q * 4 + r;
#pragma unroll
            for (int j = 0; j < 4; j++) {
                int n = bn * 128 + wn * 64 + j * 16 + mr;
                float vv = acc[i][j][r];
                if (n < nscale) vv *= qscale;
                C[(size_t)m * N + n] = f2bf(vv);
            }
        }
}

// Same GEMM, fp32 residual in + fp32 out (o-proj + residual spine).
__global__ __launch_bounds__(256) void gemm_bt_resid_kernel(
    const __hip_bfloat16* __restrict__ A,
    const __hip_bfloat16* __restrict__ Bm,
    const float* __restrict__ resid,
    float* __restrict__ C,
    int M, int N, int K)
{
    __shared__ __attribute__((aligned(16))) __hip_bfloat16 As[128 * 32];
    __shared__ __attribute__((aligned(16))) __hip_bfloat16 Bs[128 * 32];
    int tid = threadIdx.x;
    int bm = blockIdx.y, bn = blockIdx.x;
    int lane = tid & 63, wv = tid >> 6;
    int wm = wv >> 1, wn = wv & 1;
    int q = lane >> 4, mr = lane & 15;

    f32x4 acc[4][4] = {};

    for (int k0 = 0; k0 < K; k0 += 32) {
#pragma unroll
        for (int s = 0; s < 2; s++) {
            int e = (s * 256 + tid) * 8;
            int r = e >> 5, c = e & 31;
            GLOAD_LDS16(&A[(size_t)(bm * 128 + r) * K + k0 + c], &As[e]);
            GLOAD_LDS16(&Bm[(size_t)(bn * 128 + r) * K + k0 + c], &Bs[e]);
        }
        __syncthreads();
        bf16x8 af[4], bfr[4];
#pragma unroll
        for (int i = 0; i < 4; i++)
            af[i] = *(const bf16x8*)(&As[(wm * 64 + i * 16 + mr) * 32 + q * 8]);
#pragma unroll
        for (int j = 0; j < 4; j++)
            bfr[j] = *(const bf16x8*)(&Bs[(wn * 64 + j * 16 + mr) * 32 + q * 8]);
#pragma unroll
        for (int i = 0; i < 4; i++)
#pragma unroll
            for (int j = 0; j < 4; j++)
                acc[i][j] = __builtin_amdgcn_mfma_f32_16x16x32_bf16(af[i], bfr[j], acc[i][j], 0, 0, 0);
        __syncthreads();
    }

#pragma unroll
    for (int i = 0; i < 4; i++)
#pragma unroll
        for (int r = 0; r < 4; r++) {
            int m = bm * 128 + wm * 64 + i * 16 + q * 4 + r;
#pragma unroll
            for (int j = 0; j < 4; j++) {
                int n = bn * 128 + wn * 64 + j * 16 + mr;
                size_t idx = (size_t)m * N + n;
                C[idx] = resid[idx] + acc[i][j][r];
            }
        }
}

// ---------------------------------------------------------------------------
// Kernel 3: causal flash attention. Round-5 structure (double-buffered K/V,
// ONE barrier/iter, paired query tiles qt0=31-z / qt1=z) + static half-key
// split: block (z,bh,half) does keys-half `half` of both segments -> every
// block runs exactly 16 or 17 iterations; 1024 blocks = 4 blocks/CU (40 KB).
// Partials: halfA -> obuf (local layout), halfB -> attn_out (global layout),
// unnormalized, plus m/l; merged by attn_merge_kernel.
// Q pre-scaled by SCALE2 in GEMM; softmax in exp2 domain.
// ---------------------------------------------------------------------------
__global__ __launch_bounds__(256, 4) void attn_kernel(
    const __hip_bfloat16* __restrict__ qkv,
    __hip_bfloat16* __restrict__ attn_out,
    __hip_bfloat16* __restrict__ obuf,   // [1024 tiles][64][64]
    float* __restrict__ mbuf,            // [1024][2][64]
    float* __restrict__ lbuf)            // [1024][2][64]
{
    __shared__ __attribute__((aligned(16))) __hip_bfloat16 Ks[2][64 * 64];
    __shared__ __attribute__((aligned(16))) __hip_bfloat16 Vts[2][64 * 64]; // [dim][key]
    __shared__ __attribute__((aligned(16))) __hip_bfloat16 Ps[4 * 16 * 64];

    int j = blockIdx.x;                  // 0..1023
    int bh = j & 31, half = (j >> 5) & 1, z = j >> 6;
    int qt0 = 31 - z, qt1 = z;
    int n0 = qt0 + 1, n1 = qt1 + 1;
    int h0 = (n0 + 1) >> 1, h1n = (n1 + 1) >> 1;
    int a0 = half ? h0 : 0, b0 = half ? n0 : h0;
    int a1 = half ? h1n : 0, b1 = half ? n1 : h1n;
    int c0 = b0 - a0, c1 = b1 - a1, niter = c0 + c1;   // always 16 or 17; c0>=8

    int b = bh >> 4, h = bh & 15;
    int tid = threadIdx.x, lane = tid & 63, wv = tid >> 6;
    int q = lane >> 4, mr = lane & 15;
    int m8 = mr & 7;

    const size_t rs3 = 3 * D_;
    const __hip_bfloat16* qp = qkv + (size_t)(b * T_) * rs3 + h * HD_;
    const __hip_bfloat16* kp = qp + D_;
    const __hip_bfloat16* vp = qp + 2 * D_;

    // staging roles
    int sr = tid >> 2;              // K row (key) 0..63
    int sc = (tid & 3) * 16;        // K col start
    int lc0 = sc >> 3;
    int swk = sr & 7;
    int kk_ = (tid & 31) * 2;       // V key (even)
    int dd = (tid >> 5) * 8;        // V dim chunk base
    int vlc = kk_ >> 3, voff = kk_ & 7;

    // Q fragments for segment 0 (wave-private 16 rows)
    bf16x8 aq0, aq1, aqn0, aqn1;
    {
        const __hip_bfloat16* qrow = qp + (size_t)(qt0 * 64 + wv * 16 + mr) * rs3;
        aq0 = *(const bf16x8*)(qrow + q * 8);
        aq1 = *(const bf16x8*)(qrow + 32 + q * 8);
    }

    // prefetch first K/V tile (a0 of qt0) and stage into buffer 0
    bf16x8 kr0 = *(const bf16x8*)(kp + (size_t)(a0 * 64 + sr) * rs3 + sc);
    bf16x8 kr1 = *(const bf16x8*)(kp + (size_t)(a0 * 64 + sr) * rs3 + sc + 8);
    bf16x8 vr0 = *(const bf16x8*)(vp + (size_t)(a0 * 64 + kk_) * rs3 + dd);
    bf16x8 vr1 = *(const bf16x8*)(vp + (size_t)(a0 * 64 + kk_ + 1) * rs3 + dd);
    *(bf16x8*)(&Ks[0][sr * 64 + ((lc0 ^ swk) * 8)]) = kr0;
    *(bf16x8*)(&Ks[0][sr * 64 + (((lc0 + 1) ^ swk) * 8)]) = kr1;
    {
        unsigned int* vd = (unsigned int*)&Vts[0][0];
#pragma unroll
        for (int i = 0; i < 8; i++) {
            unsigned int wd = ((unsigned int)(unsigned short)vr0[i]) |
                              (((unsigned int)(unsigned short)vr1[i]) << 16);
            vd[((dd + i) * 64 + ((vlc ^ i) * 8 + voff)) >> 1] = wd;
        }
    }
    __syncthreads();

    float m_run[4], l_run[4];
    f32x4 o_acc[4] = {};
#pragma unroll
    for (int r = 0; r < 4; r++) { m_run[r] = -INFINITY; l_run[r] = 0.f; }

    // unnormalized partial store (halfA -> obuf local, halfB -> attn_out global)
    auto store_partial = [&](int qt_) {
        int tile = qt_ * 32 + bh;
        if (half == 0) {
            size_t pb = (size_t)tile * 4096;
#pragma unroll
            for (int r = 0; r < 4; r++) {
                int row = wv * 16 + q * 4 + r;
#pragma unroll
                for (int dt = 0; dt < 4; dt++)
                    obuf[pb + (size_t)row * 64 + dt * 16 + mr] = f2bf(o_acc[dt][r]);
            }
        } else {
#pragma unroll
            for (int r = 0; r < 4; r++) {
                int trow = qt_ * 64 + wv * 16 + q * 4 + r;
                size_t obase = (size_t)(b * T_ + trow) * D_ + h * HD_;
#pragma unroll
                for (int dt = 0; dt < 4; dt++)
                    attn_out[obase + dt * 16 + mr] = f2bf(o_acc[dt][r]);
            }
        }
        if (mr == 0) {
#pragma unroll
            for (int r = 0; r < 4; r++) {
                int row = wv * 16 + q * 4 + r;
                mbuf[(tile * 2 + half) * 64 + row] = m_run[r];
                lbuf[(tile * 2 + half) * 64 + row] = l_run[r];
            }
        }
    };

    for (int s = 0; s < niter; s++) {
        int seg1 = (s >= c0);
        int qt = seg1 ? qt1 : qt0;
        int kt = seg1 ? (a1 + s - c0) : (a0 + s);
        int buf = s & 1;

        // issue register prefetches for step s+1 (consumed after compute)
        if (s + 1 < niter) {
            int sn = s + 1;
            int ktn = (sn >= c0) ? (a1 + sn - c0) : (a0 + sn);
            kr0 = *(const bf16x8*)(kp + (size_t)(ktn * 64 + sr) * rs3 + sc);
            kr1 = *(const bf16x8*)(kp + (size_t)(ktn * 64 + sr) * rs3 + sc + 8);
            vr0 = *(const bf16x8*)(vp + (size_t)(ktn * 64 + kk_) * rs3 + dd);
            vr1 = *(const bf16x8*)(vp + (size_t)(ktn * 64 + kk_ + 1) * rs3 + dd);
        }
        if (s == c0 - 1 && c1 > 0) {   // Q fragments for segment 1, one iter early
            const __hip_bfloat16* qrow = qp + (size_t)(qt1 * 64 + wv * 16 + mr) * rs3;
            aqn0 = *(const bf16x8*)(qrow + q * 8);
            aqn1 = *(const bf16x8*)(qrow + 32 + q * 8);
        }

        // S strip = Q[wv*16..+16) @ K^T (Q pre-scaled -> exp2 domain directly)
        f32x4 sv[4] = {};
        {
            const __hip_bfloat16* Kb = &Ks[buf][0];
#pragma unroll
            for (int jn = 0; jn < 4; jn++)
                sv[jn] = __builtin_amdgcn_mfma_f32_16x16x32_bf16(aq0,
                    *(const bf16x8*)(&Kb[(jn * 16 + mr) * 64 + ((q ^ m8) * 8)]), sv[jn], 0, 0, 0);
#pragma unroll
            for (int jn = 0; jn < 4; jn++)
                sv[jn] = __builtin_amdgcn_mfma_f32_16x16x32_bf16(aq1,
                    *(const bf16x8*)(&Kb[(jn * 16 + mr) * 64 + (((4 + q) ^ m8) * 8)]), sv[jn], 0, 0, 0);
        }

        if (kt == qt) {   // causal mask on the diagonal tile (wave-uniform branch)
#pragma unroll
            for (int jn = 0; jn < 4; jn++)
#pragma unroll
                for (int r = 0; r < 4; r++) {
                    int rowg = wv * 16 + q * 4 + r;
                    int colg = jn * 16 + mr;
                    if (colg > rowg) sv[jn][r] = -1e30f;
                }
        }

        // online softmax per query row (16 mr-lanes share a row at fixed q)
#pragma unroll
        for (int r = 0; r < 4; r++) {
            float m0 = fmaxf(fmaxf(sv[0][r], sv[1][r]), fmaxf(sv[2][r], sv[3][r]));
#pragma unroll
            for (int msk = 1; msk < 16; msk <<= 1)
                m0 = fmaxf(m0, __shfl_xor(m0, msk, 64));
            float mn = fmaxf(m_run[r], m0);
            float alpha = exp2f(m_run[r] - mn);
            m_run[r] = mn;
            float psum = 0.f;
#pragma unroll
            for (int jn = 0; jn < 4; jn++) {
                float p = exp2f(sv[jn][r] - mn);
                sv[jn][r] = p;
                psum += p;
            }
#pragma unroll
            for (int msk = 1; msk < 16; msk <<= 1)
                psum += __shfl_xor(psum, msk, 64);
            l_run[r] = l_run[r] * alpha + psum;
#pragma unroll
            for (int dt = 0; dt < 4; dt++)
                o_acc[dt][r] *= alpha;
        }

        // P -> LDS (per-wave region, swizzled; same-wave lgkmcnt ordering)
#pragma unroll
        for (int jn = 0; jn < 4; jn++)
#pragma unroll
            for (int r = 0; r < 4; r++) {
                int row = q * 4 + r;
                int pc = (2 * jn + (mr >> 3)) ^ (row & 7);
                Ps[wv * 1024 + row * 64 + pc * 8 + (mr & 7)] = f2bf(sv[jn][r]);
            }
#pragma unroll
        for (int kk = 0; kk < 2; kk++) {
            bf16x8 ap = *(const bf16x8*)(&Ps[wv * 1024 + mr * 64 + (((kk * 4 + q) ^ m8) * 8)]);
#pragma unroll
            for (int dt = 0; dt < 4; dt++) {
                bf16x8 bv = *(const bf16x8*)(&Vts[buf][(dt * 16 + mr) * 64 + (((kk * 4 + q) ^ m8) * 8)]);
                o_acc[dt] = __builtin_amdgcn_mfma_f32_16x16x32_bf16(ap, bv, o_acc[dt], 0, 0, 0);
            }
        }

        // stage next tile into the other buffer
        if (s + 1 < niter) {
            *(bf16x8*)(&Ks[buf ^ 1][sr * 64 + ((lc0 ^ swk) * 8)]) = kr0;
            *(bf16x8*)(&Ks[buf ^ 1][sr * 64 + (((lc0 + 1) ^ swk) * 8)]) = kr1;
            unsigned int* vd = (unsigned int*)&Vts[buf ^ 1][0];
#pragma unroll
            for (int i = 0; i < 8; i++) {
                unsigned int wd = ((unsigned int)(unsigned short)vr0[i]) |
                                  (((unsigned int)(unsigned short)vr1[i]) << 16);
                vd[((dd + i) * 64 + ((vlc ^ i) * 8 + voff)) >> 1] = wd;
            }
        }
        __syncthreads();

        if (s == c0 - 1) {
            store_partial(qt0);
#pragma unroll
            for (int r = 0; r < 4; r++) { m_run[r] = -INFINITY; l_run[r] = 0.f; }
#pragma unroll
            for (int dt = 0; dt < 4; dt++) o_acc[dt] = (f32x4){0.f, 0.f, 0.f, 0.f};
            aq0 = aqn0; aq1 = aqn1;
        }
    }

    store_partial(qt1);   // zeros + m=-inf if c1==0 (merge weight -> 0)
}

// ---------------------------------------------------------------------------
// Kernel 3b: merge half-key partials (flash combine, exp2 domain).
// halfA partial in obuf (tile-local layout), halfB partial in attn_out
// (final layout, unnormalized); result overwrites attn_out.
// ---------------------------------------------------------------------------
__global__ __launch_bounds__(256) void attn_merge_kernel(
    const __hip_bfloat16* __restrict__ obuf,
    const float* __restrict__ mbuf,
    const float* __restrict__ lbuf,
    __hip_bfloat16* __restrict__ attn_out)
{
    int s = blockIdx.x;             // tile 0..1023
    int qt = s >> 5, bh = s & 31;
    int b = bh >> 4, h = bh & 15;
    int t = threadIdx.x;
    int row = t >> 2, cg = (t & 3) * 16;
    float m0 = mbuf[(s * 2 + 0) * 64 + row], m1 = mbuf[(s * 2 + 1) * 64 + row];
    float l0 = lbuf[(s * 2 + 0) * 64 + row], l1 = lbuf[(s * 2 + 1) * 64 + row];
    float mm = fmaxf(m0, m1);
    float w0 = exp2f(m0 - mm), w1 = exp2f(m1 - mm);
    float inv = 1.0f / (l0 * w0 + l1 * w1);
    const __hip_bfloat16* p0 = obuf + (size_t)s * 4096 + row * 64 + cg;
    size_t ob = (size_t)(b * T_ + qt * 64 + row) * D_ + h * HD_ + cg;
#pragma unroll
    for (int c = 0; c < 16; c++) {
        float v = (bf2f(p0[c]) * w0 + bf2f(attn_out[ob + c]) * w1) * inv;
        attn_out[ob + c] = f2bf(v);
    }
}

// ---------------------------------------------------------------------------
// Kernel 5: h = rmsnorm(xn,w2)*gamma+beta; rotations+silu; out = xn + r - h.
// ---------------------------------------------------------------------------
__global__ __launch_bounds__(256) void final_kernel(
    const float* __restrict__ xn,
    const float* __restrict__ gamma,
    const float* __restrict__ beta,
    const float* __restrict__ w2,
    const float* __restrict__ angles,
    const float* __restrict__ gate,
    const float* __restrict__ bias,
    const int* __restrict__ pi,
    const int* __restrict__ pj,
    const int* __restrict__ flag,
    void* __restrict__ outp)
{
    __shared__ float rbuf[D_];
    __shared__ float red[4];
    int row = blockIdx.x, t = threadIdx.x;
    int f = *flag;
    float eps = f ? 1.1920929e-7f : 0.0078125f;
    const float* xr = xn + (size_t)row * D_;
    float x4[4];
    float ss = 0.f;
#pragma unroll
    for (int c = 0; c < 4; c++) { x4[c] = xr[t * 4 + c]; ss += x4[c] * x4[c]; }
#pragma unroll
    for (int m = 32; m; m >>= 1) ss += __shfl_xor(ss, m, 64);
    int wv = t >> 6;
    if ((t & 63) == 0) red[wv] = ss;
    __syncthreads();
    float scale = rsqrtf((red[0] + red[1] + red[2] + red[3]) * (1.0f / D_) + eps);
    float hloc[4];
#pragma unroll
    for (int c = 0; c < 4; c++) {
        int e = t * 4 + c;
        float hv = x4[c] * scale * w2[e] * gamma[e] + beta[e];
        hloc[c] = hv;
        rbuf[e] = hv;
    }
    __syncthreads();
    for (int p = 0; p < NP_; p++) {
        float a = angles[p * P_ + t];
        float ca = __cosf(a), sa = __sinf(a);
        int ip = pi[p * P_ + t], jp = pj[p * P_ + t];
        float hi = rbuf[ip], hj = rbuf[jp];
        rbuf[ip] = hi * ca - hj * sa;
        rbuf[jp] = hi * sa + hj * ca;
        __syncthreads();
#pragma unroll
        for (int c = 0; c < 4; c++) {
            int e = t * 4 + c;
            float v = rbuf[e] * gate[p * D_ + e] + bias[p * D_ + e];
            rbuf[e] = v / (1.f + __expf(-v));
        }
        __syncthreads();
    }
#pragma unroll
    for (int c = 0; c < 4; c++) {
        int e = t * 4 + c;
        float ov = x4[c] + rbuf[e] - hloc[c];
        size_t idx = (size_t)row * D_ + e;
        if (f) ((float*)outp)[idx] = ov;
        else   ((__hip_bfloat16*)outp)[idx] = f2bf(ov);
    }
}

// ---------------------------------------------------------------------------
extern "C" void kernel_launch(void* const* d_in, const int* in_sizes, int n_in,
                              void* d_out, int out_size, void* d_ws, size_t ws_size,
                              hipStream_t stream)
{
    const void* x      = d_in[0];
    const void* gamma  = d_in[1];
    const void* beta   = d_in[2];
    const void* qkv_w  = d_in[3];
    const void* o_w    = d_in[4];
    const void* n1w    = d_in[5];
    const void* n2w    = d_in[6];
    const void* angles = d_in[7];
    const void* gate   = d_in[8];
    const void* bias   = d_in[9];
    const int* pi = (const int*)d_in[10];
    const int* pj = (const int*)d_in[11];

    const int M = B_ * T_;
    char* ws = (char*)d_ws;
    const size_t MB = 1u << 20;
    int*   flag   = (int*)ws;
    float* smalls = (float*)(ws + 4096);       // 11008 floats, 44 KB
    float* gf   = smalls;
    float* bf   = smalls + 1024;
    float* n1f  = smalls + 2048;
    float* n2f  = smalls + 3072;
    float* angf = smalls + 4096;
    float* gtf  = smalls + 4864;
    float* bif  = smalls + 7936;
    float*          xf32 = (float*)         (ws +  1 * MB);  // 16 MB [M,D]
    __hip_bfloat16* wbf  = (__hip_bfloat16*)(ws + 17 * MB);  //  6 MB [3D,D]
    __hip_bfloat16* owbf = (__hip_bfloat16*)(ws + 23 * MB);  //  2 MB [D,D]
    __hip_bfloat16* h1   = (__hip_bfloat16*)(ws + 25 * MB);  //  8 MB [M,D] (h / attn out)
    __hip_bfloat16* qkv  = (__hip_bfloat16*)(ws + 33 * MB);  // 24 MB [M,3D]
    float*          xnew = (float*)         (ws + 33 * MB);  // 16 MB, aliases dead qkv
    __hip_bfloat16* obuf = (__hip_bfloat16*)(ws + 57 * MB);  //  8 MB halfA partials
    float*          mbuf = (float*)         (ws + 65 * MB);  // 512 KB
    float*          lbuf = (float*)         (ws + 65 * MB + 512 * 1024);

    detect_kernel<<<1, 256, 0, stream>>>((const unsigned short*)x, flag);

    cvt_small_kernel<<<43, 256, 0, stream>>>(gamma, beta, n1w, n2w, angles, gate, bias,
                                             smalls, flag);
    cvt16_kernel<<<(3 * D_ * D_ + 255) / 256, 256, 0, stream>>>(qkv_w, wbf, 3 * D_ * D_, flag);
    cvt16_kernel<<<(D_ * D_ + 255) / 256, 256, 0, stream>>>(o_w, owbf, D_ * D_, flag);

    rmsnorm1_kernel<<<M, 256, 0, stream>>>(x, gf, bf, n1f, flag, h1, xf32);

    gemm_bt_bf16_kernel<<<dim3(3 * D_ / 128, M / 128), 256, 0, stream>>>(
        h1, wbf, qkv, M, 3 * D_, D_, D_, SCALE2);

    attn_kernel<<<1024, 256, 0, stream>>>(qkv, h1, obuf, mbuf, lbuf);
    attn_merge_kernel<<<1024, 256, 0, stream>>>(obuf, mbuf, lbuf, h1);

    gemm_bt_resid_kernel<<<dim3(D_ / 128, M / 128), 256, 0, stream>>>(
        h1, owbf, xf32, xnew, M, D_, D_);

    final_kernel<<<M, 256, 0, stream>>>(xnew, gf, bf, n2f, angf, gtf, bif,
                                        pi, pj, flag, d_out);
}

// Round 8
// 251.730 us; speedup vs baseline: 1.2189x; 1.2189x over previous
//
#include <hip/hip_runtime.h>
#include <hip/hip_bf16.h>

#define B_ 2
#define T_ 2048
#define D_ 1024
#define H_ 16
#define HD_ 64
#define NP_ 3
#define P_ 256

// log2(e)/sqrt(64): folded into Q in the QKV-GEMM epilogue; softmax in exp2 domain
#define SCALE2 0.18033688011112042f

typedef short bf16x8 __attribute__((ext_vector_type(8)));
typedef float f32x4 __attribute__((ext_vector_type(4)));

__device__ __forceinline__ float bf2f(__hip_bfloat16 v) { return __bfloat162float(v); }
__device__ __forceinline__ __hip_bfloat16 f2bf(float v) { return __float2bfloat16(v); }

__device__ __forceinline__ unsigned pack2bf(float a, float b) {
    union { __hip_bfloat16 h; unsigned short u; } ua, ub;
    ua.h = f2bf(a); ub.h = f2bf(b);
    return (unsigned)ua.u | ((unsigned)ub.u << 16);
}

#define GLOAD_LDS16(gp, lp) \
    __builtin_amdgcn_global_load_lds( \
        (const __attribute__((address_space(1))) void*)(gp), \
        (__attribute__((address_space(3))) void*)(lp), 16, 0, 0)

// ---------------------------------------------------------------------------
// Kernel 0: input dtype detect (fp32 reinterpreted as bf16 shows huge exps).
// ---------------------------------------------------------------------------
__global__ __launch_bounds__(256) void detect_kernel(
    const unsigned short* __restrict__ xs, int* __restrict__ flag)
{
    __shared__ int cnt;
    if (threadIdx.x == 0) cnt = 0;
    __syncthreads();
    int bad = 0;
    for (int i = threadIdx.x; i < 16384; i += 256) {
        int e = (xs[i] >> 7) & 0xFF;
        if (e >= 0xB8) bad++;
    }
    if (bad) atomicAdd(&cnt, bad);
    __syncthreads();
    if (threadIdx.x == 0) *flag = (cnt >= 8) ? 1 : 0;
}

// both weight matrices (qkv_w then o_w) -> bf16 in one launch
__global__ __launch_bounds__(256) void cvt16_2_kernel(
    const void* __restrict__ a, const void* __restrict__ bsrc,
    __hip_bfloat16* __restrict__ da, __hip_bfloat16* __restrict__ db,
    int na, int ntot, const int* __restrict__ flag)
{
    int i = blockIdx.x * 256 + threadIdx.x;
    if (i >= ntot) return;
    int f = *flag;
    if (i < na)
        da[i] = f ? f2bf(((const float*)a)[i]) : ((const __hip_bfloat16*)a)[i];
    else {
        int k = i - na;
        db[k] = f ? f2bf(((const float*)bsrc)[k]) : ((const __hip_bfloat16*)bsrc)[k];
    }
}

// all 7 small fp32 parameter arrays in one launch -> contiguous fp32 block
__global__ __launch_bounds__(256) void cvt_small_kernel(
    const void* __restrict__ g,  const void* __restrict__ b,
    const void* __restrict__ n1, const void* __restrict__ n2,
    const void* __restrict__ ang, const void* __restrict__ gt,
    const void* __restrict__ bi,
    float* __restrict__ dst, const int* __restrict__ flag)
{
    int i = blockIdx.x * 256 + threadIdx.x;
    if (i >= 11008) return;
    const void* src; int off;
    if      (i < 1024) { src = g;   off = i; }
    else if (i < 2048) { src = b;   off = i - 1024; }
    else if (i < 3072) { src = n1;  off = i - 2048; }
    else if (i < 4096) { src = n2;  off = i - 3072; }
    else if (i < 4864) { src = ang; off = i - 4096; }
    else if (i < 7936) { src = gt;  off = i - 4864; }
    else               { src = bi;  off = i - 7936; }
    dst[i] = (*flag) ? ((const float*)src)[off]
                     : bf2f(((const __hip_bfloat16*)src)[off]);
}

// ---------------------------------------------------------------------------
// Kernel 1: h = rmsnorm(x,w)*gamma+beta (bf16 out) and xcopy = x as fp32.
// ---------------------------------------------------------------------------
__global__ __launch_bounds__(256) void rmsnorm1_kernel(
    const void* __restrict__ xraw,
    const float* __restrict__ gamma,
    const float* __restrict__ beta,
    const float* __restrict__ w,
    const int* __restrict__ flag,
    __hip_bfloat16* __restrict__ out,
    float* __restrict__ xcopy)
{
    int row = blockIdx.x;
    int t = threadIdx.x;
    int f = *flag;
    float eps = f ? 1.1920929e-7f : 0.0078125f;
    float v[4];
    if (f) {
        const float4 xv = ((const float4*)((const float*)xraw + (size_t)row * D_))[t];
        v[0] = xv.x; v[1] = xv.y; v[2] = xv.z; v[3] = xv.w;
    } else {
        const __hip_bfloat16* xr = (const __hip_bfloat16*)xraw + (size_t)row * D_;
#pragma unroll
        for (int c = 0; c < 4; c++) v[c] = bf2f(xr[t * 4 + c]);
    }
    float ss = 0.f;
#pragma unroll
    for (int c = 0; c < 4; c++) ss += v[c] * v[c];
#pragma unroll
    for (int m = 32; m; m >>= 1) ss += __shfl_xor(ss, m, 64);
    __shared__ float red[4];
    int wv = t >> 6;
    if ((t & 63) == 0) red[wv] = ss;
    __syncthreads();
    float scale = rsqrtf((red[0] + red[1] + red[2] + red[3]) * (1.0f / D_) + eps);
#pragma unroll
    for (int c = 0; c < 4; c++) {
        int e = t * 4 + c;
        size_t idx = (size_t)row * D_ + e;
        xcopy[idx] = v[c];
        out[idx] = f2bf(v[c] * scale * w[e] * gamma[e] + beta[e]);
    }
}

// ---------------------------------------------------------------------------
// Kernel 2: C = A @ B^T bf16 out. 128x128, BK=32, global_load_lds width=16.
// Columns n < nscale get scaled by qscale (folds attention score scale into Q).
// ---------------------------------------------------------------------------
__global__ __launch_bounds__(256) void gemm_bt_bf16_kernel(
    const __hip_bfloat16* __restrict__ A,
    const __hip_bfloat16* __restrict__ Bm,
    __hip_bfloat16* __restrict__ C,
    int M, int N, int K, int nscale, float qscale)
{
    __shared__ __attribute__((aligned(16))) __hip_bfloat16 As[128 * 32];
    __shared__ __attribute__((aligned(16))) __hip_bfloat16 Bs[128 * 32];
    int tid = threadIdx.x;
    int bm = blockIdx.y, bn = blockIdx.x;
    int lane = tid & 63, wv = tid >> 6;
    int wm = wv >> 1, wn = wv & 1;
    int q = lane >> 4, mr = lane & 15;

    f32x4 acc[4][4] = {};

    for (int k0 = 0; k0 < K; k0 += 32) {
#pragma unroll
        for (int s = 0; s < 2; s++) {
            int e = (s * 256 + tid) * 8;
            int r = e >> 5, c = e & 31;
            GLOAD_LDS16(&A[(size_t)(bm * 128 + r) * K + k0 + c], &As[e]);
            GLOAD_LDS16(&Bm[(size_t)(bn * 128 + r) * K + k0 + c], &Bs[e]);
        }
        __syncthreads();
        bf16x8 af[4], bfr[4];
#pragma unroll
        for (int i = 0; i < 4; i++)
            af[i] = *(const bf16x8*)(&As[(wm * 64 + i * 16 + mr) * 32 + q * 8]);
#pragma unroll
        for (int j = 0; j < 4; j++)
            bfr[j] = *(const bf16x8*)(&Bs[(wn * 64 + j * 16 + mr) * 32 + q * 8]);
#pragma unroll
        for (int i = 0; i < 4; i++)
#pragma unroll
            for (int j = 0; j < 4; j++)
                acc[i][j] = __builtin_amdgcn_mfma_f32_16x16x32_bf16(af[i], bfr[j], acc[i][j], 0, 0, 0);
        __syncthreads();
    }

#pragma unroll
    for (int i = 0; i < 4; i++)
#pragma unroll
        for (int r = 0; r < 4; r++) {
            int m = bm * 128 + wm * 64 + i * 16 + q * 4 + r;
#pragma unroll
            for (int j = 0; j < 4; j++) {
                int n = bn * 128 + wn * 64 + j * 16 + mr;
                float vv = acc[i][j][r];
                if (n < nscale) vv *= qscale;
                C[(size_t)m * N + n] = f2bf(vv);
            }
        }
}

// Same GEMM, fp32 residual in + fp32 out (o-proj + residual spine).
__global__ __launch_bounds__(256) void gemm_bt_resid_kernel(
    const __hip_bfloat16* __restrict__ A,
    const __hip_bfloat16* __restrict__ Bm,
    const float* __restrict__ resid,
    float* __restrict__ C,
    int M, int N, int K)
{
    __shared__ __attribute__((aligned(16))) __hip_bfloat16 As[128 * 32];
    __shared__ __attribute__((aligned(16))) __hip_bfloat16 Bs[128 * 32];
    int tid = threadIdx.x;
    int bm = blockIdx.y, bn = blockIdx.x;
    int lane = tid & 63, wv = tid >> 6;
    int wm = wv >> 1, wn = wv & 1;
    int q = lane >> 4, mr = lane & 15;

    f32x4 acc[4][4] = {};

    for (int k0 = 0; k0 < K; k0 += 32) {
#pragma unroll
        for (int s = 0; s < 2; s++) {
            int e = (s * 256 + tid) * 8;
            int r = e >> 5, c = e & 31;
            GLOAD_LDS16(&A[(size_t)(bm * 128 + r) * K + k0 + c], &As[e]);
            GLOAD_LDS16(&Bm[(size_t)(bn * 128 + r) * K + k0 + c], &Bs[e]);
        }
        __syncthreads();
        bf16x8 af[4], bfr[4];
#pragma unroll
        for (int i = 0; i < 4; i++)
            af[i] = *(const bf16x8*)(&As[(wm * 64 + i * 16 + mr) * 32 + q * 8]);
#pragma unroll
        for (int j = 0; j < 4; j++)
            bfr[j] = *(const bf16x8*)(&Bs[(wn * 64 + j * 16 + mr) * 32 + q * 8]);
#pragma unroll
        for (int i = 0; i < 4; i++)
#pragma unroll
            for (int j = 0; j < 4; j++)
                acc[i][j] = __builtin_amdgcn_mfma_f32_16x16x32_bf16(af[i], bfr[j], acc[i][j], 0, 0, 0);
        __syncthreads();
    }

#pragma unroll
    for (int i = 0; i < 4; i++)
#pragma unroll
        for (int r = 0; r < 4; r++) {
            int m = bm * 128 + wm * 64 + i * 16 + q * 4 + r;
#pragma unroll
            for (int j = 0; j < 4; j++) {
                int n = bn * 128 + wn * 64 + j * 16 + mr;
                size_t idx = (size_t)m * N + n;
                C[idx] = resid[idx] + acc[i][j][r];
            }
        }
}

// ---------------------------------------------------------------------------
// Kernel 3: causal flash attention. r5 grid/structure (512 paired blocks,
// double-buffered K/V, one barrier/iter) computing S^T instead of S:
//   S^T = mfma(K_frag, Q_frag): query = lane&15 -> one query per thread,
//   softmax = in-thread reduce + 2 shuffles (was 8/row); m/l/alpha scalars.
//   P^T packed to LDS via 4x ds_write_b64, read back as B-operand b128
//   (swizzle conflict-free); O^T = mfma(Vts_frag, P^T_frag).
// Q pre-scaled by SCALE2 in the QKV GEMM; softmax in exp2 domain.
// ---------------------------------------------------------------------------
__global__ __launch_bounds__(256, 4) void attn_kernel(
    const __hip_bfloat16* __restrict__ qkv,
    __hip_bfloat16* __restrict__ attn_out)
{
    __shared__ __attribute__((aligned(16))) __hip_bfloat16 Ks[2][64 * 64];
    __shared__ __attribute__((aligned(16))) __hip_bfloat16 Vts[2][64 * 64]; // [dim][key]
    __shared__ __attribute__((aligned(16))) unsigned int Pd[4 * 512];      // P^T, 2KB/wave

    int z = blockIdx.x;                 // 0..15
    int qt0 = 31 - z, qt1 = z;          // 33 iterations per block, uniform
    int bh = blockIdx.y;
    int b = bh >> 4, h = bh & 15;
    int tid = threadIdx.x, lane = tid & 63, wv = tid >> 6;
    int q = lane >> 4, mr = lane & 15;
    int m8 = mr & 7;

    const size_t rs3 = 3 * D_;
    const __hip_bfloat16* qp = qkv + (size_t)(b * T_) * rs3 + h * HD_;
    const __hip_bfloat16* kp = qp + D_;
    const __hip_bfloat16* vp = qp + 2 * D_;

    // staging roles
    int sr = tid >> 2;              // K row (key) 0..63
    int sc = (tid & 3) * 16;        // K col start
    int lc0 = sc >> 3;
    int swk = sr & 7;
    int kk_ = (tid & 31) * 2;       // V key (even)
    int dd = (tid >> 5) * 8;        // V dim chunk base
    int vlc = kk_ >> 3, voff = kk_ & 7;

    // Q fragments: lane holds Q row (wv*16 + mr); these are the B-operand
    bf16x8 aq0, aq1, aqn0, aqn1;
    {
        const __hip_bfloat16* qrow = qp + (size_t)(qt0 * 64 + wv * 16 + mr) * rs3;
        aq0 = *(const bf16x8*)(qrow + q * 8);
        aq1 = *(const bf16x8*)(qrow + 32 + q * 8);
    }

    // prefetch K/V tile 0 and stage into buffer 0
    bf16x8 kr0 = *(const bf16x8*)(kp + (size_t)sr * rs3 + sc);
    bf16x8 kr1 = *(const bf16x8*)(kp + (size_t)sr * rs3 + sc + 8);
    bf16x8 vr0 = *(const bf16x8*)(vp + (size_t)kk_ * rs3 + dd);
    bf16x8 vr1 = *(const bf16x8*)(vp + (size_t)(kk_ + 1) * rs3 + dd);
    *(bf16x8*)(&Ks[0][sr * 64 + ((lc0 ^ swk) * 8)]) = kr0;
    *(bf16x8*)(&Ks[0][sr * 64 + (((lc0 + 1) ^ swk) * 8)]) = kr1;
    {
        unsigned int* vd = (unsigned int*)&Vts[0][0];
#pragma unroll
        for (int i = 0; i < 8; i++) {
            unsigned int wd = ((unsigned int)(unsigned short)vr0[i]) |
                              (((unsigned int)(unsigned short)vr1[i]) << 16);
            vd[((dd + i) * 64 + ((vlc ^ i) * 8 + voff)) >> 1] = wd;
        }
    }
    __syncthreads();

    float m_run = -INFINITY, l_run = 0.f;
    f32x4 o_acc[4] = {};
    unsigned int* Pw = &Pd[wv * 512];
    int qloc = wv * 16 + mr;            // query row within 64-tile

    for (int s = 0; s <= 32; s++) {
        int seg1 = (s > qt0);
        int kt = seg1 ? (s - qt0 - 1) : s;
        int qt = seg1 ? qt1 : qt0;
        int buf = s & 1;

        // register prefetches for step s+1 (consumed after compute)
        if (s < 32) {
            int ktn = (s + 1 > qt0) ? (s - qt0) : (s + 1);
            kr0 = *(const bf16x8*)(kp + (size_t)(ktn * 64 + sr) * rs3 + sc);
            kr1 = *(const bf16x8*)(kp + (size_t)(ktn * 64 + sr) * rs3 + sc + 8);
            vr0 = *(const bf16x8*)(vp + (size_t)(ktn * 64 + kk_) * rs3 + dd);
            vr1 = *(const bf16x8*)(vp + (size_t)(ktn * 64 + kk_ + 1) * rs3 + dd);
        }
        if (s == qt0) {   // Q fragments for segment 1, one iter early
            const __hip_bfloat16* qrow = qp + (size_t)(qt1 * 64 + wv * 16 + mr) * rs3;
            aqn0 = *(const bf16x8*)(qrow + q * 8);
            aqn1 = *(const bf16x8*)(qrow + 32 + q * 8);
        }

        // S^T strip: D[key][query], A = K-frag, B = Q-frag (swapped operands)
        f32x4 sv[4] = {};
        {
            const __hip_bfloat16* Kb = &Ks[buf][0];
#pragma unroll
            for (int jn = 0; jn < 4; jn++)
                sv[jn] = __builtin_amdgcn_mfma_f32_16x16x32_bf16(
                    *(const bf16x8*)(&Kb[(jn * 16 + mr) * 64 + ((q ^ m8) * 8)]),
                    aq0, sv[jn], 0, 0, 0);
#pragma unroll
            for (int jn = 0; jn < 4; jn++)
                sv[jn] = __builtin_amdgcn_mfma_f32_16x16x32_bf16(
                    *(const bf16x8*)(&Kb[(jn * 16 + mr) * 64 + (((4 + q) ^ m8) * 8)]),
                    aq1, sv[jn], 0, 0, 0);
        }

        if (kt == qt) {   // causal mask: key (jn*16+q*4+r) > query (qloc)
#pragma unroll
            for (int jn = 0; jn < 4; jn++)
#pragma unroll
                for (int r = 0; r < 4; r++)
                    if (jn * 16 + q * 4 + r > qloc) sv[jn][r] = -1e30f;
        }

        // softmax: one query per thread; 16 keys in-regs + lanes {mr,+16,+32,+48}
        float mx = fmaxf(fmaxf(sv[0][0], sv[0][1]), fmaxf(sv[0][2], sv[0][3]));
#pragma unroll
        for (int jn = 1; jn < 4; jn++)
            mx = fmaxf(mx, fmaxf(fmaxf(sv[jn][0], sv[jn][1]), fmaxf(sv[jn][2], sv[jn][3])));
        mx = fmaxf(mx, __shfl_xor(mx, 16, 64));
        mx = fmaxf(mx, __shfl_xor(mx, 32, 64));
        float mn = fmaxf(m_run, mx);
        float alpha = exp2f(m_run - mn);
        m_run = mn;
        float psum = 0.f;
#pragma unroll
        for (int jn = 0; jn < 4; jn++)
#pragma unroll
            for (int r = 0; r < 4; r++) {
                float p = exp2f(sv[jn][r] - mn);
                sv[jn][r] = p;
                psum += p;
            }
        psum += __shfl_xor(psum, 16, 64);
        psum += __shfl_xor(psum, 32, 64);
        l_run = l_run * alpha + psum;
#pragma unroll
        for (int dt = 0; dt < 4; dt++)
#pragma unroll
            for (int r = 0; r < 4; r++)
                o_acc[dt][r] *= alpha;

        // P^T pack -> LDS: row = query (mr), dwords = key pairs, b64 writes.
        // Physical dword addr = mr*32 + ((dw4 ^ m8) << 2) + low2 (conflict-free).
#pragma unroll
        for (int jn = 0; jn < 4; jn++) {
            uint2 val;
            val.x = pack2bf(sv[jn][0], sv[jn][1]);
            val.y = pack2bf(sv[jn][2], sv[jn][3]);
            int dw4 = 2 * jn + (q >> 1);
            *(uint2*)(&Pw[mr * 32 + ((dw4 ^ m8) << 2) + 2 * (q & 1)]) = val;
        }

        // PV: O^T[dim][query] += V^T-frag (A) x P^T-frag (B)
#pragma unroll
        for (int kk = 0; kk < 2; kk++) {
            bf16x8 bp = *(const bf16x8*)(&Pw[mr * 32 + (((4 * kk + q) ^ m8) << 2)]);
#pragma unroll
            for (int dt = 0; dt < 4; dt++) {
                bf16x8 bv = *(const bf16x8*)(&Vts[buf][(dt * 16 + mr) * 64 + (((kk * 4 + q) ^ m8) * 8)]);
                o_acc[dt] = __builtin_amdgcn_mfma_f32_16x16x32_bf16(bv, bp, o_acc[dt], 0, 0, 0);
            }
        }

        // stage next tile into the other buffer
        if (s < 32) {
            *(bf16x8*)(&Ks[buf ^ 1][sr * 64 + ((lc0 ^ swk) * 8)]) = kr0;
            *(bf16x8*)(&Ks[buf ^ 1][sr * 64 + (((lc0 + 1) ^ swk) * 8)]) = kr1;
            unsigned int* vd = (unsigned int*)&Vts[buf ^ 1][0];
#pragma unroll
            for (int i = 0; i < 8; i++) {
                unsigned int wd = ((unsigned int)(unsigned short)vr0[i]) |
                                  (((unsigned int)(unsigned short)vr1[i]) << 16);
                vd[((dd + i) * 64 + ((vlc ^ i) * 8 + voff)) >> 1] = wd;
            }
        }
        __syncthreads();

        if (s == qt0) {
            // segment 0 output: dim = dt*16 + q*4 + r, query = mr
            float inv = 1.0f / l_run;
            int trow = qt0 * 64 + wv * 16 + mr;
            __hip_bfloat16* op = attn_out + (size_t)(b * T_ + trow) * D_ + h * HD_;
#pragma unroll
            for (int dt = 0; dt < 4; dt++) {
                uint2 val;
                val.x = pack2bf(o_acc[dt][0] * inv, o_acc[dt][1] * inv);
                val.y = pack2bf(o_acc[dt][2] * inv, o_acc[dt][3] * inv);
                *(uint2*)(op + dt * 16 + q * 4) = val;
            }
            m_run = -INFINITY; l_run = 0.f;
#pragma unroll
            for (int dt = 0; dt < 4; dt++) o_acc[dt] = (f32x4){0.f, 0.f, 0.f, 0.f};
            aq0 = aqn0; aq1 = aqn1;
        }
    }

    // segment 1 output
    {
        float inv = 1.0f / l_run;
        int trow = qt1 * 64 + wv * 16 + mr;
        __hip_bfloat16* op = attn_out + (size_t)(b * T_ + trow) * D_ + h * HD_;
#pragma unroll
        for (int dt = 0; dt < 4; dt++) {
            uint2 val;
            val.x = pack2bf(o_acc[dt][0] * inv, o_acc[dt][1] * inv);
            val.y = pack2bf(o_acc[dt][2] * inv, o_acc[dt][3] * inv);
            *(uint2*)(op + dt * 16 + q * 4) = val;
        }
    }
}

// ---------------------------------------------------------------------------
// Kernel 5: h = rmsnorm(xn,w2)*gamma+beta; rotations+silu; out = xn + r - h.
// ---------------------------------------------------------------------------
__global__ __launch_bounds__(256) void final_kernel(
    const float* __restrict__ xn,
    const float* __restrict__ gamma,
    const float* __restrict__ beta,
    const float* __restrict__ w2,
    const float* __restrict__ angles,
    const float* __restrict__ gate,
    const float* __restrict__ bias,
    const int* __restrict__ pi,
    const int* __restrict__ pj,
    const int* __restrict__ flag,
    void* __restrict__ outp)
{
    __shared__ float rbuf[D_];
    __shared__ float red[4];
    int row = blockIdx.x, t = threadIdx.x;
    int f = *flag;
    float eps = f ? 1.1920929e-7f : 0.0078125f;
    const float* xr = xn + (size_t)row * D_;
    float x4[4];
    float ss = 0.f;
#pragma unroll
    for (int c = 0; c < 4; c++) { x4[c] = xr[t * 4 + c]; ss += x4[c] * x4[c]; }
#pragma unroll
    for (int m = 32; m; m >>= 1) ss += __shfl_xor(ss, m, 64);
    int wv = t >> 6;
    if ((t & 63) == 0) red[wv] = ss;
    __syncthreads();
    float scale = rsqrtf((red[0] + red[1] + red[2] + red[3]) * (1.0f / D_) + eps);
    float hloc[4];
#pragma unroll
    for (int c = 0; c < 4; c++) {
        int e = t * 4 + c;
        float hv = x4[c] * scale * w2[e] * gamma[e] + beta[e];
        hloc[c] = hv;
        rbuf[e] = hv;
    }
    __syncthreads();
    for (int p = 0; p < NP_; p++) {
        float a = angles[p * P_ + t];
        float ca = __cosf(a), sa = __sinf(a);
        int ip = pi[p * P_ + t], jp = pj[p * P_ + t];
        float hi = rbuf[ip], hj = rbuf[jp];
        rbuf[ip] = hi * ca - hj * sa;
        rbuf[jp] = hi * sa + hj * ca;
        __syncthreads();
#pragma unroll
        for (int c = 0; c < 4; c++) {
            int e = t * 4 + c;
            float v = rbuf[e] * gate[p * D_ + e] + bias[p * D_ + e];
            rbuf[e] = v / (1.f + __expf(-v));
        }
        __syncthreads();
    }
#pragma unroll
    for (int c = 0; c < 4; c++) {
        int e = t * 4 + c;
        float ov = x4[c] + rbuf[e] - hloc[c];
        size_t idx = (size_t)row * D_ + e;
        if (f) ((float*)outp)[idx] = ov;
        else   ((__hip_bfloat16*)outp)[idx] = f2bf(ov);
    }
}

// ---------------------------------------------------------------------------
extern "C" void kernel_launch(void* const* d_in, const int* in_sizes, int n_in,
                              void* d_out, int out_size, void* d_ws, size_t ws_size,
                              hipStream_t stream)
{
    const void* x      = d_in[0];
    const void* gamma  = d_in[1];
    const void* beta   = d_in[2];
    const void* qkv_w  = d_in[3];
    const void* o_w    = d_in[4];
    const void* n1w    = d_in[5];
    const void* n2w    = d_in[6];
    const void* angles = d_in[7];
    const void* gate   = d_in[8];
    const void* bias   = d_in[9];
    const int* pi = (const int*)d_in[10];
    const int* pj = (const int*)d_in[11];

    const int M = B_ * T_;
    char* ws = (char*)d_ws;
    const size_t MB = 1u << 20;
    int*   flag   = (int*)ws;
    float* smalls = (float*)(ws + 4096);       // 11008 floats, 44 KB
    float* gf   = smalls;
    float* bf   = smalls + 1024;
    float* n1f  = smalls + 2048;
    float* n2f  = smalls + 3072;
    float* angf = smalls + 4096;
    float* gtf  = smalls + 4864;
    float* bif  = smalls + 7936;
    float*          xf32 = (float*)         (ws +  1 * MB);  // 16 MB [M,D]
    __hip_bfloat16* wbf  = (__hip_bfloat16*)(ws + 17 * MB);  //  6 MB [3D,D]
    __hip_bfloat16* owbf = (__hip_bfloat16*)(ws + 23 * MB);  //  2 MB [D,D]
    __hip_bfloat16* h1   = (__hip_bfloat16*)(ws + 25 * MB);  //  8 MB [M,D] (h / attn out)
    __hip_bfloat16* qkv  = (__hip_bfloat16*)(ws + 33 * MB);  // 24 MB [M,3D]
    float*          xnew = (float*)         (ws + 33 * MB);  // 16 MB, aliases dead qkv

    detect_kernel<<<1, 256, 0, stream>>>((const unsigned short*)x, flag);

    cvt_small_kernel<<<43, 256, 0, stream>>>(gamma, beta, n1w, n2w, angles, gate, bias,
                                             smalls, flag);
    cvt16_2_kernel<<<(4 * D_ * D_ + 255) / 256, 256, 0, stream>>>(
        qkv_w, o_w, wbf, owbf, 3 * D_ * D_, 4 * D_ * D_, flag);

    rmsnorm1_kernel<<<M, 256, 0, stream>>>(x, gf, bf, n1f, flag, h1, xf32);

    gemm_bt_bf16_kernel<<<dim3(3 * D_ / 128, M / 128), 256, 0, stream>>>(
        h1, wbf, qkv, M, 3 * D_, D_, D_, SCALE2);

    attn_kernel<<<dim3(16, B_ * H_), 256, 0, stream>>>(qkv, h1);

    gemm_bt_resid_kernel<<<dim3(D_ / 128, M / 128), 256, 0, stream>>>(
        h1, owbf, xf32, xnew, M, D_, D_);

    final_kernel<<<M, 256, 0, stream>>>(xnew, gf, bf, n2f, angf, gtf, bif,
                                        pi, pj, flag, d_out);
}